// Round 4
// baseline (66.252 us; speedup 1.0000x reference)
//
#include <hip/hip_runtime.h>
#include <hip/hip_bf16.h>

// Problem constants (fixed by reference):
#define SS 512
#define HH 768
#define LL 32
#define DD 1536   // 2*H
#define MM 2048   // B*L rows
#define KK DD     // GEMM K (full, 1536)

typedef float f32x4 __attribute__((ext_vector_type(4)));
typedef short bf16x8 __attribute__((ext_vector_type(8)));

__device__ __forceinline__ unsigned short f2bf(float x) {
    union { float f; unsigned u; } v; v.f = x;
    unsigned r = v.u + 0x7fff + ((v.u >> 16) & 1);   // round-to-nearest-even
    return (unsigned short)(r >> 16);
}

// ---------------------------------------------------------------------------
// Kernel 1 (fused prep): blocks [0,2048) build clause_h rows (bf16),
// blocks [2048,4352) convert W_pool f32->bf16, blocks [4352,4360) init out.
// All three are independent; fusing lets them run concurrently.
// ---------------------------------------------------------------------------
__global__ __launch_bounds__(256)
void prep(const float* __restrict__ seq, const int* __restrict__ pos,
          const float* __restrict__ Wp, const float* __restrict__ bo,
          unsigned short* __restrict__ Abf, unsigned short* __restrict__ Wbf,
          float* __restrict__ out) {
    int blk = blockIdx.x;
    int tid = threadIdx.x;
    if (blk < MM) {
        // ---- build clause_h row blk = [mean(768) | cls(768)] in bf16 ----
        int b = blk >> 5;
        int l = blk & 31;
        const int* pb = pos + b * (LL + 1);
        int start = pb[l] + 1;
        int end   = pb[l + 1] + 1;
        if (l == LL - 1) end += 1;      // last clause also takes the SEP token
        float inv = 1.0f / (float)(end - start);
        const float* base = seq + (size_t)b * SS * HH;
        float a0 = 0.f, a1 = 0.f, a2 = 0.f;
        for (int t = start; t < end; ++t) {
            const float* p = base + (size_t)t * HH;
            a0 += p[tid]; a1 += p[tid + 256]; a2 += p[tid + 512];
        }
        unsigned short* o = Abf + (size_t)blk * DD;
        o[tid]       = f2bf(a0 * inv);
        o[tid + 256] = f2bf(a1 * inv);
        o[tid + 512] = f2bf(a2 * inv);
        o[HH + tid]       = f2bf(base[tid]);       // CLS = token 0
        o[HH + tid + 256] = f2bf(base[tid + 256]);
        o[HH + tid + 512] = f2bf(base[tid + 512]);
    } else if (blk < MM + (DD * DD / 1024)) {
        // ---- convert W_pool: 2304 blocks x 256 threads x 4 elems ----
        int i = ((blk - MM) * 256 + tid) * 4;
        float4 v = *(const float4*)(Wp + i);
        ushort4 o;
        o.x = f2bf(v.x); o.y = f2bf(v.y); o.z = f2bf(v.z); o.w = f2bf(v.w);
        *(ushort4*)(Wbf + i) = o;
    } else {
        // ---- init logits to b_out ----
        int i = (blk - MM - DD * DD / 1024) * 256 + tid;
        if (i < MM) out[i] = bo[0];
    }
}

// ---------------------------------------------------------------------------
// Kernel 2: barrier-free register-direct MFMA GEMM.
// Each wave owns a 64x64 output tile; 2 waves/block split K (768 each, 24
// steps of 32). No LDS staging, no barriers in the K-loop -> compiler
// pipelines global loads across steps; 1536 waves (1.5/SIMD, 3 blocks/CU)
// drift independently. End: one LDS exchange to combine K-halves, fused
// tanh(.+b_pool)�W_out epilogue, 16-lane shfl reduce, atomicAdd.
// Block mapping: 2D XCD chunking (8x12 tiles/XCD = 3.9MB, fits 4MB L2).
// ---------------------------------------------------------------------------
__global__ __launch_bounds__(128, 2)
void gemm_reg(const unsigned short* __restrict__ A,   // [MM][KK] bf16
              const unsigned short* __restrict__ Bm,  // [DD][KK] bf16
              const float* __restrict__ bp,           // [DD]
              const float* __restrict__ Wo,           // [DD]
              float* __restrict__ out) {              // [MM]
    __shared__ f32x4 xch[2][2][4][64];   // [m-half][mm][n][lane] = 16 KB
    const int tid  = threadIdx.x;
    const int w    = tid >> 6;           // 0/1: K-half
    const int lane = tid & 63;
    const int fr   = lane & 15;
    const int fq   = lane >> 4;

    // XCD-aware 2D chunking: xcd = flat%8 (HW round-robin), chunk 8(bm) x 12(bn)
    const int flat = blockIdx.x;         // 0..767
    const int c = flat & 7;
    const int i = flat >> 3;             // 0..95
    const int bm = (c >> 1) * 8 + (i & 7);    // 0..31
    const int bn = (c & 1) * 12 + (i >> 3);   // 0..23
    const int brow = bm * 64;
    const int bcol = bn * 64;

    const unsigned short* pA = A  + (size_t)(brow + fr) * KK + w * 768 + fq * 8;
    const unsigned short* pB = Bm + (size_t)(bcol + fr) * KK + w * 768 + fq * 8;

    f32x4 acc[4][4] = {};

    #pragma unroll 4
    for (int t = 0; t < 24; ++t) {
        const int k = t * 32;
        bf16x8 a0 = *(const bf16x8*)(pA + k);
        bf16x8 a1 = *(const bf16x8*)(pA + 16 * KK + k);
        bf16x8 a2 = *(const bf16x8*)(pA + 32 * KK + k);
        bf16x8 a3 = *(const bf16x8*)(pA + 48 * KK + k);
        bf16x8 b0 = *(const bf16x8*)(pB + k);
        bf16x8 b1 = *(const bf16x8*)(pB + 16 * KK + k);
        bf16x8 b2 = *(const bf16x8*)(pB + 32 * KK + k);
        bf16x8 b3 = *(const bf16x8*)(pB + 48 * KK + k);
        acc[0][0] = __builtin_amdgcn_mfma_f32_16x16x32_bf16(a0, b0, acc[0][0], 0, 0, 0);
        acc[0][1] = __builtin_amdgcn_mfma_f32_16x16x32_bf16(a0, b1, acc[0][1], 0, 0, 0);
        acc[0][2] = __builtin_amdgcn_mfma_f32_16x16x32_bf16(a0, b2, acc[0][2], 0, 0, 0);
        acc[0][3] = __builtin_amdgcn_mfma_f32_16x16x32_bf16(a0, b3, acc[0][3], 0, 0, 0);
        acc[1][0] = __builtin_amdgcn_mfma_f32_16x16x32_bf16(a1, b0, acc[1][0], 0, 0, 0);
        acc[1][1] = __builtin_amdgcn_mfma_f32_16x16x32_bf16(a1, b1, acc[1][1], 0, 0, 0);
        acc[1][2] = __builtin_amdgcn_mfma_f32_16x16x32_bf16(a1, b2, acc[1][2], 0, 0, 0);
        acc[1][3] = __builtin_amdgcn_mfma_f32_16x16x32_bf16(a1, b3, acc[1][3], 0, 0, 0);
        acc[2][0] = __builtin_amdgcn_mfma_f32_16x16x32_bf16(a2, b0, acc[2][0], 0, 0, 0);
        acc[2][1] = __builtin_amdgcn_mfma_f32_16x16x32_bf16(a2, b1, acc[2][1], 0, 0, 0);
        acc[2][2] = __builtin_amdgcn_mfma_f32_16x16x32_bf16(a2, b2, acc[2][2], 0, 0, 0);
        acc[2][3] = __builtin_amdgcn_mfma_f32_16x16x32_bf16(a2, b3, acc[2][3], 0, 0, 0);
        acc[3][0] = __builtin_amdgcn_mfma_f32_16x16x32_bf16(a3, b0, acc[3][0], 0, 0, 0);
        acc[3][1] = __builtin_amdgcn_mfma_f32_16x16x32_bf16(a3, b1, acc[3][1], 0, 0, 0);
        acc[3][2] = __builtin_amdgcn_mfma_f32_16x16x32_bf16(a3, b2, acc[3][2], 0, 0, 0);
        acc[3][3] = __builtin_amdgcn_mfma_f32_16x16x32_bf16(a3, b3, acc[3][3], 0, 0, 0);
    }

    // ---- combine K-halves: wave w keeps m-half w, ships the other half ----
    const int ow = 1 - w;
    #pragma unroll
    for (int mm = 0; mm < 2; ++mm)
        #pragma unroll
        for (int n = 0; n < 4; ++n)
            xch[ow][mm][n][lane] = acc[ow * 2 + mm][n];
    __syncthreads();

    // ---- fused epilogue on kept half: tanh(acc+b_pool)�W_out, row-reduce ----
    #pragma unroll
    for (int mm = 0; mm < 2; ++mm) {
        const int m = w * 2 + mm;
        float vsum[4] = {0.f, 0.f, 0.f, 0.f};
        #pragma unroll
        for (int n = 0; n < 4; ++n) {
            f32x4 s = acc[m][n] + xch[w][mm][n][lane];
            const int col = bcol + n * 16 + fr;
            const float wo_ = Wo[col];
            const float pb_ = bp[col];
            #pragma unroll
            for (int r = 0; r < 4; ++r) {
                float x = s[r] + pb_;
                float th = 1.f - 2.f / (__expf(2.f * x) + 1.f);  // tanh(x)
                vsum[r] += th * wo_;
            }
        }
        #pragma unroll
        for (int r = 0; r < 4; ++r) {
            float v = vsum[r];
            v += __shfl_xor(v, 1, 16);
            v += __shfl_xor(v, 2, 16);
            v += __shfl_xor(v, 4, 16);
            v += __shfl_xor(v, 8, 16);
            if (fr == 0)
                atomicAdd(&out[brow + m * 16 + fq * 4 + r], v);
        }
    }
}

// ---------------------------------------------------------------------------
extern "C" void kernel_launch(void* const* d_in, const int* in_sizes, int n_in,
                              void* d_out, int out_size, void* d_ws, size_t ws_size,
                              hipStream_t stream) {
    const float* seq   = (const float*)d_in[0];  // [B,S,H]
    // d_in[1] = context_h (unused by reference)
    const float* Wp    = (const float*)d_in[2];  // [D,D]
    const float* bp    = (const float*)d_in[3];  // [D]
    const float* Wo    = (const float*)d_in[4];  // [D]
    const float* bo    = (const float*)d_in[5];  // scalar
    const int*   pos   = (const int*)d_in[6];    // [B,L+1]
    // d_in[7] = doc_lens (unused by reference)
    float* out = (float*)d_out;                  // [B,L] = 2048

    unsigned short* Abf = (unsigned short*)d_ws;       // [MM][DD] bf16
    unsigned short* Wbf = Abf + (size_t)MM * DD;       // [DD][DD] bf16

    const int nconv = DD * DD / 1024;                  // 2304
    const int ninit = (MM + 255) / 256;                // 8
    prep<<<MM + nconv + ninit, 256, 0, stream>>>(seq, pos, Wp, bo, Abf, Wbf, out);
    gemm_reg<<<768, 128, 0, stream>>>(Abf, Wbf, bp, Wo, out);
}

// Round 5
// 41.344 us; speedup vs baseline: 1.6024x; 1.6024x over previous
//
#include <hip/hip_runtime.h>
#include <hip/hip_bf16.h>

// Problem constants (fixed by reference):
#define SS 512
#define HH 768
#define LL 32
#define DD 1536   // 2*H
#define MM 2048   // B*L rows
#define KK DD     // GEMM K

typedef float f32x4 __attribute__((ext_vector_type(4)));
typedef short bf16x8 __attribute__((ext_vector_type(8)));

__device__ __forceinline__ unsigned short f2bf(float x) {
    union { float f; unsigned u; } v; v.f = x;
    unsigned r = v.u + 0x7fff + ((v.u >> 16) & 1);   // round-to-nearest-even
    return (unsigned short)(r >> 16);
}

__device__ __forceinline__ void gload16(const unsigned short* g, unsigned short* l) {
    // async global->LDS, 16B/lane; LDS dest = wave-uniform base + lane*16
    __builtin_amdgcn_global_load_lds(
        (const __attribute__((address_space(1))) void*)g,
        (__attribute__((address_space(3))) void*)l, 16, 0, 0);
}

// ---------------------------------------------------------------------------
// Fused prep: blocks [0,2048) build clause_h rows (bf16); [2048,4352) convert
// W_pool f32->bf16; [4352,4360) init logits to b_out.
// ---------------------------------------------------------------------------
__global__ __launch_bounds__(256)
void prep(const float* __restrict__ seq, const int* __restrict__ pos,
          const float* __restrict__ Wp, const float* __restrict__ bo,
          unsigned short* __restrict__ Abf, unsigned short* __restrict__ Wbf,
          float* __restrict__ out) {
    int blk = blockIdx.x;
    int tid = threadIdx.x;
    if (blk < MM) {
        int b = blk >> 5;
        int l = blk & 31;
        const int* pb = pos + b * (LL + 1);
        int start = pb[l] + 1;
        int end   = pb[l + 1] + 1;
        if (l == LL - 1) end += 1;      // last clause also takes the SEP token
        float inv = 1.0f / (float)(end - start);
        const float* base = seq + (size_t)b * SS * HH;
        float a0 = 0.f, a1 = 0.f, a2 = 0.f;
        for (int t = start; t < end; ++t) {
            const float* p = base + (size_t)t * HH;
            a0 += p[tid]; a1 += p[tid + 256]; a2 += p[tid + 512];
        }
        unsigned short* o = Abf + (size_t)blk * DD;
        o[tid]       = f2bf(a0 * inv);
        o[tid + 256] = f2bf(a1 * inv);
        o[tid + 512] = f2bf(a2 * inv);
        o[HH + tid]       = f2bf(base[tid]);       // CLS = token 0
        o[HH + tid + 256] = f2bf(base[tid + 256]);
        o[HH + tid + 512] = f2bf(base[tid + 512]);
    } else if (blk < MM + (DD * DD / 1024)) {
        int i = ((blk - MM) * 256 + tid) * 4;
        float4 v = *(const float4*)(Wp + i);
        ushort4 o;
        o.x = f2bf(v.x); o.y = f2bf(v.y); o.z = f2bf(v.z); o.w = f2bf(v.w);
        *(ushort4*)(Wbf + i) = o;
    } else {
        int i = (blk - MM - DD * DD / 1024) * 256 + tid;
        if (i < MM) out[i] = bo[0];
    }
}

// ---------------------------------------------------------------------------
// GEMM: 64x64 tile, 4 waves (2x2, wave tile 32x32), BK=64, 3-deep LDS
// pipeline with counted vmcnt, raw s_barrier, XOR-swizzled LDS (source-side
// pre-swizzle + swizzled ds_read). 768 blocks = 3 blocks/CU, all resident.
// XCD chunking: 8(bm) x 12(bn) 64^2-tiles per XCD = 3.75 MB, fits 4 MB L2.
// Fused epilogue: tanh(acc+b_pool)*W_out, 16-lane shfl reduce, atomicAdd.
// ---------------------------------------------------------------------------
__global__ __launch_bounds__(256, 3)
void gemm_mfma(const unsigned short* __restrict__ A,   // [MM][KK] bf16
               const unsigned short* __restrict__ Bm,  // [DD][KK] bf16
               const float* __restrict__ bp,           // [DD]
               const float* __restrict__ Wo,           // [DD]
               float* __restrict__ out) {              // [MM]
    __shared__ unsigned short As[3 * 4096];  // 3 bufs x 64x64 bf16 = 24 KB
    __shared__ unsigned short Bs[3 * 4096];  // 24 KB  (total 48 KB -> 3 blk/CU)
    const int tid  = threadIdx.x;
    const int wid  = tid >> 6;
    const int lane = tid & 63;
    const int fr   = lane & 15;
    const int fq   = lane >> 4;
    const int wr   = wid >> 1, wc = wid & 1;

    // XCD-aware chunking: xcd = blk%8 (HW round-robin); chunk 8 bm x 12 bn
    const int blk = blockIdx.x;             // 0..767
    const int c = blk & 7;
    const int i = blk >> 3;                 // 0..95
    const int bm = ((c >> 1) << 3) + (i & 7);     // 0..31
    const int bn = (c & 1) * 12 + (i >> 3);       // 0..23
    const int brow = bm * 64;
    const int bcol = bn * 64;

    // staging: thread t -> row t>>3 (and +32), 16B chunk (t&7)^(row&7)
    // (source pre-swizzle; LDS dest stays linear per rule #21)
    const int srow = tid >> 3;              // 0..31 ; +32 for second half
    const int sc   = (tid & 7) ^ (srow & 7);      // (srow+32)&7 == srow&7
    const unsigned short* gA = A  + (size_t)(brow + srow) * KK + sc * 8;
    const unsigned short* gB = Bm + (size_t)(bcol + srow) * KK + sc * 8;
    unsigned short* asW = As + wid * 512;   // wave-uniform LDS dest base
    unsigned short* bsW = Bs + wid * 512;

#define STAGE(buf, kt) do {                                          \
        gload16(gA + (kt) * 64,           asW + (buf) * 4096);       \
        gload16(gA + (kt) * 64 + 32 * KK, asW + (buf) * 4096 + 2048);\
        gload16(gB + (kt) * 64,           bsW + (buf) * 4096);       \
        gload16(gB + (kt) * 64 + 32 * KK, bsW + (buf) * 4096 + 2048);\
    } while (0)

    // swizzled fragment-read offsets: slot(h) = ((h<<2)|fq) ^ (row&7);
    // row&7 == fr&7 for all frag rows (row = base16*k + fr)
    const int s0 = fq ^ (fr & 7);
    const int s1 = s0 ^ 4;
    const int rA = wr * 32 + fr;            // m adds 16
    const int rB = wc * 32 + fr;            // n adds 16
    const int oA00 = rA * 64 + s0 * 8, oA01 = rA * 64 + s1 * 8;
    const int oA10 = oA00 + 16 * 64,   oA11 = oA01 + 16 * 64;
    const int oB00 = rB * 64 + s0 * 8, oB01 = rB * 64 + s1 * 8;
    const int oB10 = oB00 + 16 * 64,   oB11 = oB01 + 16 * 64;

    f32x4 acc[2][2] = {};

    STAGE(0, 0); STAGE(1, 1); STAGE(2, 2);

#define BODY(t, buf) do {                                                     \
        __builtin_amdgcn_sched_barrier(0);                                    \
        if ((t) <= 21)      asm volatile("s_waitcnt vmcnt(8)" ::: "memory");  \
        else if ((t) == 22) asm volatile("s_waitcnt vmcnt(4)" ::: "memory");  \
        else                asm volatile("s_waitcnt vmcnt(0)" ::: "memory");  \
        __builtin_amdgcn_s_barrier();                                         \
        const unsigned short* as_ = As + (buf) * 4096;                        \
        const unsigned short* bs_ = Bs + (buf) * 4096;                        \
        bf16x8 a00 = *(const bf16x8*)(as_ + oA00);                            \
        bf16x8 a01 = *(const bf16x8*)(as_ + oA01);                            \
        bf16x8 a10 = *(const bf16x8*)(as_ + oA10);                            \
        bf16x8 a11 = *(const bf16x8*)(as_ + oA11);                            \
        bf16x8 b00 = *(const bf16x8*)(bs_ + oB00);                            \
        bf16x8 b01 = *(const bf16x8*)(bs_ + oB01);                            \
        bf16x8 b10 = *(const bf16x8*)(bs_ + oB10);                            \
        bf16x8 b11 = *(const bf16x8*)(bs_ + oB11);                            \
        asm volatile("s_waitcnt lgkmcnt(0)" ::: "memory");                    \
        __builtin_amdgcn_s_barrier();                                         \
        if ((t) + 3 < 24) STAGE(buf, (t) + 3);                                \
        acc[0][0] = __builtin_amdgcn_mfma_f32_16x16x32_bf16(a00, b00, acc[0][0], 0, 0, 0); \
        acc[0][0] = __builtin_amdgcn_mfma_f32_16x16x32_bf16(a01, b01, acc[0][0], 0, 0, 0); \
        acc[0][1] = __builtin_amdgcn_mfma_f32_16x16x32_bf16(a00, b10, acc[0][1], 0, 0, 0); \
        acc[0][1] = __builtin_amdgcn_mfma_f32_16x16x32_bf16(a01, b11, acc[0][1], 0, 0, 0); \
        acc[1][0] = __builtin_amdgcn_mfma_f32_16x16x32_bf16(a10, b00, acc[1][0], 0, 0, 0); \
        acc[1][0] = __builtin_amdgcn_mfma_f32_16x16x32_bf16(a11, b01, acc[1][0], 0, 0, 0); \
        acc[1][1] = __builtin_amdgcn_mfma_f32_16x16x32_bf16(a10, b10, acc[1][1], 0, 0, 0); \
        acc[1][1] = __builtin_amdgcn_mfma_f32_16x16x32_bf16(a11, b11, acc[1][1], 0, 0, 0); \
    } while (0)

    #pragma unroll
    for (int t = 0; t < 24; ++t) {
        BODY(t, t % 3);          // fully unrolled: t, t%3 compile-time
    }
#undef BODY
#undef STAGE

    // epilogue: C/D layout col=lane&15, row=(lane>>4)*4+reg (m89-verified)
    #pragma unroll
    for (int m = 0; m < 2; ++m) {
        float vsum[4] = {0.f, 0.f, 0.f, 0.f};
        #pragma unroll
        for (int n = 0; n < 2; ++n) {
            const int col = bcol + wc * 32 + n * 16 + fr;
            const float wo_ = Wo[col];
            const float pb_ = bp[col];
            #pragma unroll
            for (int r = 0; r < 4; ++r) {
                float x = acc[m][n][r] + pb_;
                float th = 1.f - 2.f / (__expf(2.f * x) + 1.f);  // tanh(x)
                vsum[r] += th * wo_;
            }
        }
        #pragma unroll
        for (int r = 0; r < 4; ++r) {
            float v = vsum[r];
            v += __shfl_xor(v, 1, 16);
            v += __shfl_xor(v, 2, 16);
            v += __shfl_xor(v, 4, 16);
            v += __shfl_xor(v, 8, 16);
            if (fr == 0)
                atomicAdd(&out[brow + wr * 32 + m * 16 + fq * 4 + r], v);
        }
    }
}

// ---------------------------------------------------------------------------
extern "C" void kernel_launch(void* const* d_in, const int* in_sizes, int n_in,
                              void* d_out, int out_size, void* d_ws, size_t ws_size,
                              hipStream_t stream) {
    const float* seq   = (const float*)d_in[0];  // [B,S,H]
    // d_in[1] = context_h (unused by reference)
    const float* Wp    = (const float*)d_in[2];  // [D,D]
    const float* bp    = (const float*)d_in[3];  // [D]
    const float* Wo    = (const float*)d_in[4];  // [D]
    const float* bo    = (const float*)d_in[5];  // scalar
    const int*   pos   = (const int*)d_in[6];    // [B,L+1]
    // d_in[7] = doc_lens (unused by reference)
    float* out = (float*)d_out;                  // [B,L] = 2048

    unsigned short* Abf = (unsigned short*)d_ws;       // [MM][DD] bf16
    unsigned short* Wbf = Abf + (size_t)MM * DD;       // [DD][DD] bf16

    const int nconv = DD * DD / 1024;                  // 2304
    const int ninit = (MM + 255) / 256;                // 8
    prep<<<MM + nconv + ninit, 256, 0, stream>>>(seq, pos, Wp, bo, Abf, Wbf, out);
    gemm_mfma<<<768, 256, 0, stream>>>(Abf, Wbf, bp, Wo, out);
}